// Round 6
// baseline (756.471 us; speedup 1.0000x reference)
//
#include <hip/hip_runtime.h>
#include <hip/hip_bf16.h>
#include <stdint.h>

#define DEVI __device__ __forceinline__

namespace {

constexpr int B = 8, T = 2048, C = 3, E = 256, KW = 15, BN = 32;
constexpr float EPS = 1e-5f;

constexpr int XPAD = 8;              // conv_in reach: +/-7
constexpr int XS   = T + 2*XPAD;     // 2064
constexpr int HPAD = 224;            // max reach: 7*32
constexpr int HS   = T + 2*HPAD;     // 2496

// workspace layout (float units)
constexpr size_t O_MEAN = 0;
constexpr size_t O_STD  = 32;
constexpr size_t O_QN   = 64;
constexpr size_t XBUF   = (size_t)B*C*XS;
constexpr size_t O_KN   = O_QN + XBUF;
constexpr size_t HBUF   = (size_t)3*B*BN*HS;
constexpr size_t O_HA   = O_KN + XBUF;
constexpr size_t O_HB   = O_HA + HBUF;
constexpr size_t O_Q    = O_HB + HBUF;
constexpr size_t QBUF_H = (size_t)B*T*E/2;       // bf16 buffers in float units
constexpr size_t O_K    = O_Q + QBUF_H;
constexpr size_t O_V    = O_K + QBUF_H;          // V^T tiled [b][t/32][e][32] bf16
constexpr size_t O_PO_HI= O_V + QBUF_H;          // splits 0..2; end 66.06MB (proven r1)
constexpr size_t O_WP   = O_PO_HI;               // repacked weights; clobbered only by attn
constexpr size_t WP_MID = (size_t)3*5*BN*KW*BN;  // [net][layer][i][kk][o32]
constexpr size_t WP_OUT = (size_t)3*BN*E;        // [net][i][e]
// split 3 + m/l overlay regions consumed before attn writes them:
constexpr size_t O_PO_LO= O_QN;
constexpr size_t O_MLM  = O_PO_LO + QBUF_H;
constexpr size_t O_MLL  = O_MLM + (size_t)4*B*T;

typedef __attribute__((ext_vector_type(8))) short bfrag;
typedef __attribute__((ext_vector_type(4))) float f32x4;

DEVI short f2bf(float f){            // fp32 -> bf16 bits, RNE
  uint32_t u = __builtin_bit_cast(uint32_t, f);
  u = u + 0x7fffu + ((u >> 16) & 1u);
  return (short)(u >> 16);
}
DEVI float bf2f(unsigned short u){
  uint32_t x = (uint32_t)u << 16;
  return __builtin_bit_cast(float, x);
}

// ---- fused: RevIN stats+normalize (blocks 0..23, pads included) + weight repack (blocks 24..1019)
__global__ __launch_bounds__(256) void k_front(
    const float* __restrict__ query_in, const float* __restrict__ key_in,
    const float* __restrict__ revin_w, const float* __restrict__ revin_b,
    const float* __restrict__ qm, const float* __restrict__ km, const float* __restrict__ vm,
    const float* __restrict__ qo, const float* __restrict__ ko, const float* __restrict__ vo,
    float* __restrict__ ws){
  const int bid = blockIdx.x;
  const int tid = threadIdx.x;
  if (bid < B*C){
    float* qn = ws + O_QN;
    float* kn = ws + O_KN;
    const int b = bid / C, c = bid % C;
    float s = 0.f, s2 = 0.f;
    for (int t = tid; t < T; t += 256){
      float v = key_in[((size_t)(b*T) + t)*C + c];
      s += v; s2 += v*v;
    }
    __shared__ float r1[256], r2[256];
    __shared__ float sstat[2];
    r1[tid] = s; r2[tid] = s2;
    __syncthreads();
    for (int st = 128; st > 0; st >>= 1){
      if (tid < st){ r1[tid] += r1[tid+st]; r2[tid] += r2[tid+st]; }
      __syncthreads();
    }
    if (tid == 0){
      float m = r1[0] / (float)T;
      float var = r2[0] / (float)T - m*m;
      float sd = sqrtf(var + EPS);
      ws[O_MEAN + bid] = m; ws[O_STD + bid] = sd;
      sstat[0] = m; sstat[1] = 1.f / sd;
    }
    __syncthreads();
    const float m = sstat[0], inv = sstat[1];
    const float wv = revin_w[c], bv = revin_b[c];
    float* qrow = qn + ((size_t)(b*C) + c)*XS;
    float* krow = kn + ((size_t)(b*C) + c)*XS;
    for (int t = tid; t < T; t += 256){
      size_t src = ((size_t)(b*T) + t)*C + c;
      qrow[XPAD + t] = (query_in[src] - m) * inv * wv + bv;
      krow[XPAD + t] = (key_in[src]   - m) * inv * wv + bv;
    }
    if (tid < XPAD){
      qrow[tid] = 0.f; qrow[XPAD + T + tid] = 0.f;
      krow[tid] = 0.f; krow[XPAD + T + tid] = 0.f;
    }
  } else {
    float* wp_mid = ws + O_WP;
    float* wp_out = ws + O_WP + WP_MID;
    size_t idx = (size_t)(bid - B*C)*256 + tid;     // exact: 996*256 = WP_MID+WP_OUT
    if (idx < WP_MID){
      int q = (int)idx;
      int o = q & 31; int r = q >> 5; int kk = r % 15; r /= 15;
      int i = r & 31; r >>= 5; int l = r % 5; int n = r / 5;
      const float* src = (n==0 ? qm : (n==1 ? km : vm));
      wp_mid[idx] = src[(((size_t)l*BN + o)*BN + i)*KW + kk];
    } else if (idx < WP_MID + WP_OUT){
      int j = (int)(idx - WP_MID);
      int e = j & 255; int r = j >> 8; int i = r & 31; int n = r >> 5;
      const float* src = (n==0 ? qo : (n==1 ? ko : vo));
      wp_out[j] = src[(size_t)e*BN + i];
    }
  }
}

// conv in: C=3 -> BN=32, k=15, dil=1, ReLU. grid = 3*B*BN; also zeroes its output row pads.
__global__ __launch_bounds__(256) void k_conv_in(
    const float* __restrict__ qn, const float* __restrict__ kn,
    const float* __restrict__ wq, const float* __restrict__ bq,
    const float* __restrict__ wk, const float* __restrict__ bk,
    const float* __restrict__ wv, const float* __restrict__ bv,
    float* __restrict__ hout){
  __shared__ float xs[C*XS];
  const int net = blockIdx.x / (B*BN);
  const int rem = blockIdx.x % (B*BN);
  const int b = rem / BN, o = rem % BN;
  const float* x    = (net==0 ? qn : kn) + (size_t)b*C*XS;
  const float* w    = (net==0 ? wq : (net==1 ? wk : wv)) + o*C*KW;
  const float* bias = (net==0 ? bq : (net==1 ? bk : bv));
  for (int i = threadIdx.x; i < C*XS; i += 256) xs[i] = x[i];
  __syncthreads();
  const float bo = bias[o];
  float* orow = hout + (((size_t)(net*B + b))*BN + o)*HS;
  for (int j = 0; j < 8; j++){
    int t = j*256 + threadIdx.x;
    float acc = bo;
    #pragma unroll
    for (int c = 0; c < C; c++)
      #pragma unroll
      for (int kk = 0; kk < KW; kk++)
        acc += xs[c*XS + XPAD + t + kk - 7] * w[c*KW + kk];
    orow[HPAD + t] = fmaxf(acc, 0.f);
  }
  if (threadIdx.x < HPAD){
    orow[threadIdx.x] = 0.f;
    orow[HPAD + T + threadIdx.x] = 0.f;
  }
}

// dilated conv BN->BN, k=15, ReLU. grid = 384 x 512 thr (net, b, ttile 128).
// wave -> uniform 4-o group; repacked weights [i][kk][o] -> s_load_dwordx4 per (i,kk).
// tt==0/15 blocks zero the output pads.
template<int DIL>
__global__ __launch_bounds__(512) void k_conv_mid(
    const float* __restrict__ hin, float* __restrict__ hout,
    const float* __restrict__ wp,
    const float* __restrict__ bq, const float* __restrict__ bk, const float* __restrict__ bv,
    int layer){
  const int net = blockIdx.x >> 7;
  const int rem = blockIdx.x & 127;
  const int b = rem >> 4;
  const int tt = rem & 15;
  const int og = __builtin_amdgcn_readfirstlane(threadIdx.x >> 6);
  const int lane = threadIdx.x & 63;
  const int t0 = tt*128 + lane*2;
  const float* w    = wp + ((size_t)(net*5 + layer))*BN*KW*BN + og*4;
  const float* bias = (net==0 ? bq : (net==1 ? bk : bv)) + layer*BN + og*4;
  float a0[4] = {0.f,0.f,0.f,0.f}, a1[4] = {0.f,0.f,0.f,0.f};
  const float* xin = hin + ((size_t)(net*B + b))*BN*HS + HPAD + t0 - 7*DIL;
  for (int i = 0; i < BN; i++){
    const float* xr = xin + (size_t)i*HS;
    #pragma unroll
    for (int kk = 0; kk < KW; kk++){
      const float2 xv = *(const float2*)(xr + kk*DIL);
      const float4 w4 = *(const float4*)&w[(i*KW + kk)*BN];
      a0[0] += w4.x*xv.x; a1[0] += w4.x*xv.y;
      a0[1] += w4.y*xv.x; a1[1] += w4.y*xv.y;
      a0[2] += w4.z*xv.x; a1[2] += w4.z*xv.y;
      a0[3] += w4.w*xv.x; a1[3] += w4.w*xv.y;
    }
  }
  #pragma unroll
  for (int r = 0; r < 4; r++){
    float bb = bias[r];
    float2 o2 = {fmaxf(a0[r]+bb, 0.f), fmaxf(a1[r]+bb, 0.f)};
    *(float2*)&hout[(((size_t)(net*B + b))*BN + og*4 + r)*HS + HPAD + t0] = o2;
  }
  if (tt == 0){
    for (int idx = threadIdx.x; idx < BN*HPAD; idx += 512){
      int o = idx / HPAD, j = idx % HPAD;
      hout[(((size_t)(net*B + b))*BN + o)*HS + j] = 0.f;
    }
  } else if (tt == 15){
    for (int idx = threadIdx.x; idx < BN*HPAD; idx += 512){
      int o = idx / HPAD, j = idx % HPAD;
      hout[(((size_t)(net*B + b))*BN + o)*HS + HPAD + T + j] = 0.f;
    }
  }
}

// 1x1 conv BN -> E, bf16 out; q pre-scaled by E^-0.5; net 2 writes V^T tiles [b][t/32][e][32].
// grid = 1536 x 256. (r4-proven)
__global__ __launch_bounds__(256) void k_conv_out(
    const float* __restrict__ hin, const float* __restrict__ wpo,
    const float* __restrict__ bq, const float* __restrict__ bk, const float* __restrict__ bv,
    unsigned short* __restrict__ qo, unsigned short* __restrict__ ko, unsigned short* __restrict__ vt){
  const int net = blockIdx.x >> 9;
  const int rem = blockIdx.x & 511;
  const int b = rem >> 6;
  const int tt = (rem & 63) >> 2;
  const int eq = rem & 3;
  const int wave = __builtin_amdgcn_readfirstlane(threadIdx.x >> 6);
  const int lane = threadIdx.x & 63;
  const int t0 = tt*128 + lane*2;
  const int e_base = eq*64 + wave*16;
  const float* w    = wpo + (size_t)net*BN*E;
  const float* bias = (net==0 ? bq : (net==1 ? bk : bv)) + e_base;
  float acc[16][2];
  #pragma unroll
  for (int j = 0; j < 16; j++){ acc[j][0] = 0.f; acc[j][1] = 0.f; }
  const float* hb = hin + (((size_t)(net*B + b))*BN)*HS + HPAD + t0;
  for (int i = 0; i < BN; i++){
    const float2 xv = *(const float2*)(hb + (size_t)i*HS);
    #pragma unroll
    for (int u = 0; u < 4; u++){
      const float4 w4 = *(const float4*)&w[i*E + e_base + u*4];
      acc[u*4+0][0] += w4.x*xv.x; acc[u*4+0][1] += w4.x*xv.y;
      acc[u*4+1][0] += w4.y*xv.x; acc[u*4+1][1] += w4.y*xv.y;
      acc[u*4+2][0] += w4.z*xv.x; acc[u*4+2][1] += w4.z*xv.y;
      acc[u*4+3][0] += w4.w*xv.x; acc[u*4+3][1] += w4.w*xv.y;
    }
  }
  if (net < 2){
    const float scale = (net==0) ? 0.0625f : 1.0f;
    unsigned short* outp = (net==0 ? qo : ko);
    #pragma unroll
    for (int z = 0; z < 2; z++){
      bfrag pk[2];
      #pragma unroll
      for (int j = 0; j < 16; j++)
        pk[j>>3][j&7] = f2bf((acc[j][z] + bias[j]) * scale);
      size_t dst = ((size_t)(b*T) + t0 + z)*E + e_base;
      *(bfrag*)&outp[dst]     = pk[0];
      *(bfrag*)&outp[dst + 8] = pk[1];
    }
  } else {
    unsigned short* tile = vt + (((size_t)(b*64) + (t0>>5))*256)*32 + (t0 & 31);
    #pragma unroll
    for (int j = 0; j < 16; j++){
      uint32_t pk = (uint32_t)(unsigned short)f2bf(acc[j][0] + bias[j])
                  | ((uint32_t)(unsigned short)f2bf(acc[j][1] + bias[j]) << 16);
      *(uint32_t*)&tile[(size_t)(e_base + j)*32] = pk;
    }
  }
}

// flash attention, barrier-free: K and V^T MFMA B-fragments loaded DIRECTLY from global
// (contiguous 8-short groups; L1/L2-resident tiles). No LDS staging, no __syncthreads.
// BQ=64 (4 waves x 16 q-rows), BK=32, split-K=4. grid = B*32*4 = 1024 x 256 thr.
// mfma_f32_16x16x32_bf16: A[m=l16][k=quad*8+j], B[k=quad*8+j][n=l16], D[row=quad*4+reg][col=l16].
__global__ __launch_bounds__(256, 2) void k_attn(
    const unsigned short* __restrict__ qbuf, const unsigned short* __restrict__ kbuf,
    const unsigned short* __restrict__ vt,
    unsigned short* __restrict__ PO_hi, unsigned short* __restrict__ PO_lo,
    float* __restrict__ MLm, float* __restrict__ MLl){
  __shared__ __align__(16) short Ps[4*16*40];   // per-wave P tile [q][key], pad 40

  const int sk   = blockIdx.x & 3;
  const int qt   = (blockIdx.x >> 2) & 31;
  const int b    = blockIdx.x >> 7;
  const int tid  = threadIdx.x;
  const int wave = tid >> 6;
  const int lane = tid & 63;
  const int quad = lane >> 4;
  const int l16  = lane & 15;
  const int qrow_base = qt*64 + wave*16;

  bfrag a_q[8];
  {
    const unsigned short* qrow = qbuf + ((size_t)(b*T) + qrow_base + l16)*E + quad*8;
    #pragma unroll
    for (int kt = 0; kt < 8; kt++)
      a_q[kt] = *(const bfrag*)&qrow[kt*32];
  }

  f32x4 acc_o[16];
  #pragma unroll
  for (int nt = 0; nt < 16; nt++){ f32x4 z = {0.f,0.f,0.f,0.f}; acc_o[nt] = z; }
  float m_run[4] = {-1e30f,-1e30f,-1e30f,-1e30f};
  float l_run[4] = {0.f,0.f,0.f,0.f};

  for (int kbk = sk*16; kbk < sk*16 + 16; kbk++){
    // ---- S = Q K^T : B-fragments straight from K (row-major, e contiguous) ----
    const unsigned short* kbase = kbuf + ((size_t)(b*T) + kbk*32 + l16)*E + quad*8;
    f32x4 s0a = {0,0,0,0}, s0b = {0,0,0,0}, s1a = {0,0,0,0}, s1b = {0,0,0,0};
    #pragma unroll
    for (int kt = 0; kt < 8; kt += 2){
      bfrag k0a = *(const bfrag*)(kbase + kt*32);
      bfrag k1a = *(const bfrag*)(kbase + 16*E + kt*32);
      bfrag k0b = *(const bfrag*)(kbase + (kt+1)*32);
      bfrag k1b = *(const bfrag*)(kbase + 16*E + (kt+1)*32);
      s0a = __builtin_amdgcn_mfma_f32_16x16x32_bf16(a_q[kt],   k0a, s0a, 0, 0, 0);
      s1a = __builtin_amdgcn_mfma_f32_16x16x32_bf16(a_q[kt],   k1a, s1a, 0, 0, 0);
      s0b = __builtin_amdgcn_mfma_f32_16x16x32_bf16(a_q[kt+1], k0b, s0b, 0, 0, 0);
      s1b = __builtin_amdgcn_mfma_f32_16x16x32_bf16(a_q[kt+1], k1b, s1b, 0, 0, 0);
    }
    f32x4 sac0 = s0a + s0b, sac1 = s1a + s1b;

    // ---- online softmax (rows = quad*4+rr, cols = l16 / 16+l16) ----
    float mloc[4], lloc[4], p0[4], p1[4], alpha[4];
    #pragma unroll
    for (int rr = 0; rr < 4; rr++) mloc[rr] = fmaxf(sac0[rr], sac1[rr]);
    #pragma unroll
    for (int off = 1; off < 16; off <<= 1)
      #pragma unroll
      for (int rr = 0; rr < 4; rr++) mloc[rr] = fmaxf(mloc[rr], __shfl_xor(mloc[rr], off));
    #pragma unroll
    for (int rr = 0; rr < 4; rr++){
      float mn = fmaxf(m_run[rr], mloc[rr]);
      alpha[rr] = __expf(m_run[rr] - mn);
      p0[rr] = __expf(sac0[rr] - mn);
      p1[rr] = __expf(sac1[rr] - mn);
      lloc[rr] = p0[rr] + p1[rr];
      m_run[rr] = mn;
    }
    #pragma unroll
    for (int off = 1; off < 16; off <<= 1)
      #pragma unroll
      for (int rr = 0; rr < 4; rr++) lloc[rr] += __shfl_xor(lloc[rr], off);
    #pragma unroll
    for (int rr = 0; rr < 4; rr++) l_run[rr] = l_run[rr]*alpha[rr] + lloc[rr];

    // P -> per-wave LDS (same wave writes & reads; no barrier)
    #pragma unroll
    for (int rr = 0; rr < 4; rr++){
      Ps[(wave*16 + quad*4+rr)*40 + l16]      = f2bf(p0[rr]);
      Ps[(wave*16 + quad*4+rr)*40 + 16 + l16] = f2bf(p1[rr]);
    }
    #pragma unroll
    for (int nt = 0; nt < 16; nt++)
      #pragma unroll
      for (int rr = 0; rr < 4; rr++) acc_o[nt][rr] *= alpha[rr];

    // ---- O += P V : B-fragments straight from V^T tile [e][32 keys] ----
    const unsigned short* vbase = vt + (((size_t)(b*64) + kbk)*256 + l16)*32 + quad*8;
    bfrag pa = *(const bfrag*)&Ps[(wave*16 + l16)*40 + quad*8];
    #pragma unroll
    for (int nt = 0; nt < 16; nt++){
      bfrag vf = *(const bfrag*)(vbase + (size_t)nt*16*32);
      acc_o[nt] = __builtin_amdgcn_mfma_f32_16x16x32_bf16(pa, vf, acc_o[nt], 0, 0, 0);
    }
  }

  // ---- epilogue: store normalized partial O (bf16) + m,l ----
  unsigned short* PO = (sk < 3) ? (PO_hi + (size_t)sk*((size_t)B*T*E)) : PO_lo;
  #pragma unroll
  for (int rr = 0; rr < 4; rr++){
    float inv_l = 1.f / l_run[rr];
    const int row = qrow_base + quad*4 + rr;
    const size_t off = ((size_t)(b*T) + row)*E;
    #pragma unroll
    for (int nt = 0; nt < 16; nt++)
      PO[off + nt*16 + l16] = (unsigned short)f2bf(acc_o[nt][rr] * inv_l);
    if (l16 == 0){
      const size_t rm = ((size_t)(sk*B + b))*T + row;
      MLm[rm] = m_run[rr];
      MLl[rm] = l_run[rr];
    }
  }
}

// combine 4 splits + out-projection + RevIN denorm. grid = 512 x 256. (r3-proven)
__global__ __launch_bounds__(256) void k_comb(
    const unsigned short* __restrict__ PO_hi, const unsigned short* __restrict__ PO_lo,
    const float* __restrict__ MLm, const float* __restrict__ MLl,
    const float* __restrict__ out_w, const float* __restrict__ out_b,
    const float* __restrict__ revin_w, const float* __restrict__ revin_b,
    const float* __restrict__ meanp, const float* __restrict__ stdp,
    float* __restrict__ out){
  __shared__ float wsh[3*E];
  for (int i = threadIdx.x; i < 3*E; i += 256) wsh[i] = out_w[i];
  __syncthreads();
  const int b  = blockIdx.x >> 6;
  const int rt = blockIdx.x & 63;
  const int row = rt*32 + (threadIdx.x >> 3);
  const int c8 = threadIdx.x & 7;
  const int e0 = c8*32;
  float ms[4], ls[4], wn[4];
  #pragma unroll
  for (int s2 = 0; s2 < 4; s2++){
    const size_t rm = ((size_t)(s2*B + b))*T + row;
    ms[s2] = MLm[rm]; ls[s2] = MLl[rm];
  }
  float mx = fmaxf(fmaxf(ms[0], ms[1]), fmaxf(ms[2], ms[3]));
  float wsum = 0.f;
  #pragma unroll
  for (int s2 = 0; s2 < 4; s2++){ wn[s2] = __expf(ms[s2]-mx)*ls[s2]; wsum += wn[s2]; }
  float inv = 1.f/wsum;
  #pragma unroll
  for (int s2 = 0; s2 < 4; s2++) wn[s2] *= inv;
  const unsigned short* ps[4];
  #pragma unroll
  for (int s2 = 0; s2 < 4; s2++){
    const unsigned short* base = (s2 < 3) ? (PO_hi + (size_t)s2*((size_t)B*T*E)) : PO_lo;
    ps[s2] = base + ((size_t)(b*T) + row)*E + e0;
  }
  float pr[3] = {0.f, 0.f, 0.f};
  #pragma unroll
  for (int u = 0; u < 4; u++){
    float v[8] = {0,0,0,0,0,0,0,0};
    #pragma unroll
    for (int s2 = 0; s2 < 4; s2++){
      bfrag a = *(const bfrag*)&ps[s2][u*8];
      #pragma unroll
      for (int z = 0; z < 8; z++) v[z] += wn[s2]*bf2f((unsigned short)a[z]);
    }
    #pragma unroll
    for (int z = 0; z < 8; z++){
      int e = e0 + u*8 + z;
      pr[0] += v[z]*wsh[e];
      pr[1] += v[z]*wsh[E + e];
      pr[2] += v[z]*wsh[2*E + e];
    }
  }
  #pragma unroll
  for (int c = 0; c < 3; c++){
    pr[c] += __shfl_xor(pr[c], 1);
    pr[c] += __shfl_xor(pr[c], 2);
    pr[c] += __shfl_xor(pr[c], 4);
  }
  if (c8 == 0){
    #pragma unroll
    for (int c = 0; c < 3; c++){
      float val = pr[c] + out_b[c];
      val = (val - revin_b[c]) / revin_w[c];
      val = val * stdp[b*C + c] + meanp[b*C + c];
      out[((size_t)(b*T) + row)*C + c] = val;
    }
  }
}

} // namespace

extern "C" void kernel_launch(void* const* d_in, const int* in_sizes, int n_in,
                              void* d_out, int out_size, void* d_ws, size_t ws_size,
                              hipStream_t stream){
  const float* query_in = (const float*)d_in[0];
  const float* key_in   = (const float*)d_in[1];
  const float* q_w_in   = (const float*)d_in[2];
  const float* q_b_in   = (const float*)d_in[3];
  const float* q_w_mid  = (const float*)d_in[4];
  const float* q_b_mid  = (const float*)d_in[5];
  const float* q_w_out  = (const float*)d_in[6];
  const float* q_b_out  = (const float*)d_in[7];
  const float* k_w_in   = (const float*)d_in[8];
  const float* k_b_in   = (const float*)d_in[9];
  const float* k_w_mid  = (const float*)d_in[10];
  const float* k_b_mid  = (const float*)d_in[11];
  const float* k_w_out  = (const float*)d_in[12];
  const float* k_b_out  = (const float*)d_in[13];
  const float* v_w_in   = (const float*)d_in[14];
  const float* v_b_in   = (const float*)d_in[15];
  const float* v_w_mid  = (const float*)d_in[16];
  const float* v_b_mid  = (const float*)d_in[17];
  const float* v_w_out  = (const float*)d_in[18];
  const float* v_b_out  = (const float*)d_in[19];
  const float* out_w    = (const float*)d_in[20];
  const float* out_b    = (const float*)d_in[21];
  const float* revin_w  = (const float*)d_in[22];
  const float* revin_b  = (const float*)d_in[23];
  float* ws  = (float*)d_ws;
  float* out = (float*)d_out;

  unsigned short* qb = (unsigned short*)(ws + O_Q);
  unsigned short* kb = (unsigned short*)(ws + O_K);
  unsigned short* vt = (unsigned short*)(ws + O_V);
  unsigned short* PO_hi = (unsigned short*)(ws + O_PO_HI);
  unsigned short* PO_lo = (unsigned short*)(ws + O_PO_LO);
  float* wp_mid = ws + O_WP;
  float* wp_out = ws + O_WP + WP_MID;
  float* MLm = ws + O_MLM;
  float* MLl = ws + O_MLL;

  hipLaunchKernelGGL(k_front, dim3(1020), dim3(256), 0, stream,
                     query_in, key_in, revin_w, revin_b,
                     q_w_mid, k_w_mid, v_w_mid, q_w_out, k_w_out, v_w_out, ws);
  hipLaunchKernelGGL(k_conv_in, dim3(3*B*BN), dim3(256), 0, stream,
                     ws+O_QN, ws+O_KN, q_w_in, q_b_in, k_w_in, k_b_in, v_w_in, v_b_in, ws+O_HA);
  float* ha = ws + O_HA;
  float* hb = ws + O_HB;
  hipLaunchKernelGGL(k_conv_mid<2>,  dim3(384), dim3(512), 0, stream, ha, hb,
                     wp_mid, q_b_mid, k_b_mid, v_b_mid, 0);
  hipLaunchKernelGGL(k_conv_mid<4>,  dim3(384), dim3(512), 0, stream, hb, ha,
                     wp_mid, q_b_mid, k_b_mid, v_b_mid, 1);
  hipLaunchKernelGGL(k_conv_mid<8>,  dim3(384), dim3(512), 0, stream, ha, hb,
                     wp_mid, q_b_mid, k_b_mid, v_b_mid, 2);
  hipLaunchKernelGGL(k_conv_mid<16>, dim3(384), dim3(512), 0, stream, hb, ha,
                     wp_mid, q_b_mid, k_b_mid, v_b_mid, 3);
  hipLaunchKernelGGL(k_conv_mid<32>, dim3(384), dim3(512), 0, stream, ha, hb,
                     wp_mid, q_b_mid, k_b_mid, v_b_mid, 4);
  hipLaunchKernelGGL(k_conv_out, dim3(1536), dim3(256), 0, stream,
                     hb, wp_out, q_b_out, k_b_out, v_b_out, qb, kb, vt);
  hipLaunchKernelGGL(k_attn, dim3(B*32*4), dim3(256), 0, stream, qb, kb, vt, PO_hi, PO_lo, MLm, MLl);
  hipLaunchKernelGGL(k_comb, dim3(B*T/32), dim3(256), 0, stream,
                     PO_hi, PO_lo, MLm, MLl, out_w, out_b, revin_w, revin_b, ws+O_MEAN, ws+O_STD, out);
}

// Round 7
// 520.449 us; speedup vs baseline: 1.4535x; 1.4535x over previous
//
#include <hip/hip_runtime.h>
#include <hip/hip_bf16.h>
#include <stdint.h>

#define DEVI __device__ __forceinline__

namespace {

constexpr int B = 8, T = 2048, C = 3, E = 256, KW = 15, BN = 32;
constexpr float EPS = 1e-5f;

constexpr int XPAD = 8;              // conv_in reach: +/-7
constexpr int XS   = T + 2*XPAD;     // 2064
constexpr int HPAD = 224;            // max reach: 7*32
constexpr int HS   = T + 2*HPAD;     // 2496

// workspace layout (float units)
constexpr size_t O_MEAN = 0;
constexpr size_t O_STD  = 32;
constexpr size_t O_QN   = 64;
constexpr size_t XBUF   = (size_t)B*C*XS;
constexpr size_t O_KN   = O_QN + XBUF;
constexpr size_t HBUF   = (size_t)3*B*BN*HS;
constexpr size_t O_HA   = O_KN + XBUF;
constexpr size_t O_HB   = O_HA + HBUF;
constexpr size_t O_Q    = O_HB + HBUF;
constexpr size_t QBUF_H = (size_t)B*T*E/2;       // bf16 buffers in float units
constexpr size_t O_K    = O_Q + QBUF_H;
constexpr size_t O_V    = O_K + QBUF_H;          // V^T tiled [b][t/32][e][32] bf16
constexpr size_t O_PO_HI= O_V + QBUF_H;          // splits 0..2; end 66.06MB (proven r1)
constexpr size_t O_WP   = O_PO_HI;               // repacked weights; clobbered only by attn
constexpr size_t WP_MID = (size_t)3*5*BN*KW*BN;  // [net][layer][i][kk][o32] (unused by r1-mid, kept for layout)
constexpr size_t WP_OUT = (size_t)3*BN*E;        // [net][i][e]
// split 3 + m/l overlay regions consumed before attn writes them:
constexpr size_t O_PO_LO= O_QN;
constexpr size_t O_MLM  = O_PO_LO + QBUF_H;
constexpr size_t O_MLL  = O_MLM + (size_t)4*B*T;

typedef __attribute__((ext_vector_type(8))) short bfrag;
typedef __attribute__((ext_vector_type(4))) float f32x4;

DEVI short f2bf(float f){            // fp32 -> bf16 bits, RNE
  uint32_t u = __builtin_bit_cast(uint32_t, f);
  u = u + 0x7fffu + ((u >> 16) & 1u);
  return (short)(u >> 16);
}
DEVI float bf2f(unsigned short u){
  uint32_t x = (uint32_t)u << 16;
  return __builtin_bit_cast(float, x);
}

// ---- fused: RevIN stats+normalize (blocks 0..23, pads zeroed) + weight repack (blocks 24..1019)
__global__ __launch_bounds__(256) void k_front(
    const float* __restrict__ query_in, const float* __restrict__ key_in,
    const float* __restrict__ revin_w, const float* __restrict__ revin_b,
    const float* __restrict__ qm, const float* __restrict__ km, const float* __restrict__ vm,
    const float* __restrict__ qo, const float* __restrict__ ko, const float* __restrict__ vo,
    float* __restrict__ ws){
  const int bid = blockIdx.x;
  const int tid = threadIdx.x;
  if (bid < B*C){
    float* qn = ws + O_QN;
    float* kn = ws + O_KN;
    const int b = bid / C, c = bid % C;
    float s = 0.f, s2 = 0.f;
    for (int t = tid; t < T; t += 256){
      float v = key_in[((size_t)(b*T) + t)*C + c];
      s += v; s2 += v*v;
    }
    __shared__ float r1[256], r2[256];
    __shared__ float sstat[2];
    r1[tid] = s; r2[tid] = s2;
    __syncthreads();
    for (int st = 128; st > 0; st >>= 1){
      if (tid < st){ r1[tid] += r1[tid+st]; r2[tid] += r2[tid+st]; }
      __syncthreads();
    }
    if (tid == 0){
      float m = r1[0] / (float)T;
      float var = r2[0] / (float)T - m*m;
      float sd = sqrtf(var + EPS);
      ws[O_MEAN + bid] = m; ws[O_STD + bid] = sd;
      sstat[0] = m; sstat[1] = 1.f / sd;
    }
    __syncthreads();
    const float m = sstat[0], inv = sstat[1];
    const float wv = revin_w[c], bv = revin_b[c];
    float* qrow = qn + ((size_t)(b*C) + c)*XS;
    float* krow = kn + ((size_t)(b*C) + c)*XS;
    for (int t = tid; t < T; t += 256){
      size_t src = ((size_t)(b*T) + t)*C + c;
      qrow[XPAD + t] = (query_in[src] - m) * inv * wv + bv;
      krow[XPAD + t] = (key_in[src]   - m) * inv * wv + bv;
    }
    if (tid < XPAD){
      qrow[tid] = 0.f; qrow[XPAD + T + tid] = 0.f;
      krow[tid] = 0.f; krow[XPAD + T + tid] = 0.f;
    }
  } else {
    float* wp_mid = ws + O_WP;
    float* wp_out = ws + O_WP + WP_MID;
    size_t idx = (size_t)(bid - B*C)*256 + tid;
    if (idx < WP_MID){
      int q = (int)idx;
      int o = q & 31; int r = q >> 5; int kk = r % 15; r /= 15;
      int i = r & 31; r >>= 5; int l = r % 5; int n = r / 5;
      const float* src = (n==0 ? qm : (n==1 ? km : vm));
      wp_mid[idx] = src[(((size_t)l*BN + o)*BN + i)*KW + kk];
    } else if (idx < WP_MID + WP_OUT){
      int j = (int)(idx - WP_MID);
      int e = j & 255; int r = j >> 8; int i = r & 31; int n = r >> 5;
      const float* src = (n==0 ? qo : (n==1 ? ko : vo));
      wp_out[j] = src[(size_t)e*BN + i];
    }
  }
}

// conv in: C=3 -> BN=32, k=15, dil=1, ReLU. grid = 3*B*BN, block = one (net,b,o) row.  [r1-proven]
__global__ __launch_bounds__(256) void k_conv_in(
    const float* __restrict__ qn, const float* __restrict__ kn,
    const float* __restrict__ wq, const float* __restrict__ bq,
    const float* __restrict__ wk, const float* __restrict__ bk,
    const float* __restrict__ wv, const float* __restrict__ bv,
    float* __restrict__ hout){
  __shared__ float xs[C*XS];
  __shared__ float wsh[C*KW];
  const int net = blockIdx.x / (B*BN);
  const int rem = blockIdx.x % (B*BN);
  const int b = rem / BN, o = rem % BN;
  const float* x    = (net==0 ? qn : kn) + (size_t)b*C*XS;
  const float* w    = (net==0 ? wq : (net==1 ? wk : wv)) + o*C*KW;
  const float* bias = (net==0 ? bq : (net==1 ? bk : bv));
  for (int i = threadIdx.x; i < C*XS; i += 256) xs[i] = x[i];
  if (threadIdx.x < C*KW) wsh[threadIdx.x] = w[threadIdx.x];
  __syncthreads();
  const float bo = bias[o];
  float* orow = hout + (((size_t)(net*B + b))*BN + o)*HS;
  for (int j = 0; j < 8; j++){
    int t = j*256 + threadIdx.x;
    float acc = bo;
    #pragma unroll
    for (int c = 0; c < C; c++)
      #pragma unroll
      for (int kk = 0; kk < KW; kk++)
        acc += xs[c*XS + XPAD + t + kk - 7] * wsh[c*KW + kk];
    orow[HPAD + t] = fmaxf(acc, 0.f);
  }
  if (threadIdx.x < HPAD){
    orow[threadIdx.x] = 0.f;
    orow[HPAD + T + threadIdx.x] = 0.f;
  }
}

// dilated conv BN->BN, k=15, ReLU. [r1 structure verbatim — fastest measured]
// grid = 3*128: (net, b, t-tile 128). thread = 4o x 4t, weights LDS-transposed
// [i*15+kk][o] for single ds_read_b128 per (i,kk). tt==0/15 blocks zero output pads.
template<int DIL>
__global__ __launch_bounds__(256) void k_conv_mid(
    const float* __restrict__ hin, float* __restrict__ hout,
    const float* __restrict__ wq, const float* __restrict__ wk, const float* __restrict__ wv,
    const float* __restrict__ bq, const float* __restrict__ bk, const float* __restrict__ bv,
    int layer){
  __shared__ float wt[BN*KW*BN];   // 61440 B
  const int net = blockIdx.x >> 7;
  const int rem = blockIdx.x & 127;
  const int b = rem >> 4, tt = rem & 15;
  const float* w    = (net==0 ? wq : (net==1 ? wk : wv)) + (size_t)layer*BN*BN*KW;
  const float* bias = (net==0 ? bq : (net==1 ? bk : bv)) + layer*BN;
  for (int i = threadIdx.x; i < BN*BN*KW; i += 256){
    int o = i / (BN*KW), ikk = i % (BN*KW);
    wt[ikk*BN + o] = w[i];
  }
  __syncthreads();
  const int og = threadIdx.x >> 5, ts = threadIdx.x & 31;
  float acc[4][4];
  #pragma unroll
  for (int rr = 0; rr < 4; rr++){
    float bb = bias[og*4 + rr];
    #pragma unroll
    for (int x = 0; x < 4; x++) acc[rr][x] = bb;
  }
  const float* xin = hin + ((size_t)(net*B + b))*BN*HS + HPAD + tt*128 + ts*4 - 7*DIL;
  for (int i = 0; i < BN; i++){
    const float* rowp = xin + (size_t)i*HS;
    #pragma unroll
    for (int kk = 0; kk < KW; kk++){
      const float4 w4 = *(const float4*)&wt[(i*KW + kk)*BN + og*4];
      const float* pp = rowp + kk*DIL;
      float2 x01 = *(const float2*)(pp);
      float2 x23 = *(const float2*)(pp + 2);
      float xv[4] = {x01.x, x01.y, x23.x, x23.y};
      #pragma unroll
      for (int rr = 0; rr < 4; rr++){
        const float ww = (rr==0)?w4.x:((rr==1)?w4.y:((rr==2)?w4.z:w4.w));
        #pragma unroll
        for (int x = 0; x < 4; x++) acc[rr][x] += ww * xv[x];
      }
    }
  }
  #pragma unroll
  for (int rr = 0; rr < 4; rr++){
    float* op = hout + (((size_t)(net*B + b))*BN + og*4 + rr)*HS + HPAD + tt*128 + ts*4;
    float4 o4 = {fmaxf(acc[rr][0],0.f), fmaxf(acc[rr][1],0.f), fmaxf(acc[rr][2],0.f), fmaxf(acc[rr][3],0.f)};
    *(float4*)op = o4;
  }
  if (tt == 0){
    for (int idx = threadIdx.x; idx < BN*HPAD; idx += 256){
      int o = idx / HPAD, j = idx % HPAD;
      hout[(((size_t)(net*B + b))*BN + o)*HS + j] = 0.f;
    }
  } else if (tt == 15){
    for (int idx = threadIdx.x; idx < BN*HPAD; idx += 256){
      int o = idx / HPAD, j = idx % HPAD;
      hout[(((size_t)(net*B + b))*BN + o)*HS + HPAD + T + j] = 0.f;
    }
  }
}

// 1x1 conv BN -> E, bf16 out; q pre-scaled by E^-0.5; net 2 writes V^T tiles [b][t/32][e][32].
// grid = 1536 x 256. [r4/r6-proven]
__global__ __launch_bounds__(256) void k_conv_out(
    const float* __restrict__ hin, const float* __restrict__ wpo,
    const float* __restrict__ bq, const float* __restrict__ bk, const float* __restrict__ bv,
    unsigned short* __restrict__ qo, unsigned short* __restrict__ ko, unsigned short* __restrict__ vt){
  const int net = blockIdx.x >> 9;
  const int rem = blockIdx.x & 511;
  const int b = rem >> 6;
  const int tt = (rem & 63) >> 2;
  const int eq = rem & 3;
  const int wave = __builtin_amdgcn_readfirstlane(threadIdx.x >> 6);
  const int lane = threadIdx.x & 63;
  const int t0 = tt*128 + lane*2;
  const int e_base = eq*64 + wave*16;
  const float* w    = wpo + (size_t)net*BN*E;
  const float* bias = (net==0 ? bq : (net==1 ? bk : bv)) + e_base;
  float acc[16][2];
  #pragma unroll
  for (int j = 0; j < 16; j++){ acc[j][0] = 0.f; acc[j][1] = 0.f; }
  const float* hb = hin + (((size_t)(net*B + b))*BN)*HS + HPAD + t0;
  for (int i = 0; i < BN; i++){
    const float2 xv = *(const float2*)(hb + (size_t)i*HS);
    #pragma unroll
    for (int u = 0; u < 4; u++){
      const float4 w4 = *(const float4*)&w[i*E + e_base + u*4];
      acc[u*4+0][0] += w4.x*xv.x; acc[u*4+0][1] += w4.x*xv.y;
      acc[u*4+1][0] += w4.y*xv.x; acc[u*4+1][1] += w4.y*xv.y;
      acc[u*4+2][0] += w4.z*xv.x; acc[u*4+2][1] += w4.z*xv.y;
      acc[u*4+3][0] += w4.w*xv.x; acc[u*4+3][1] += w4.w*xv.y;
    }
  }
  if (net < 2){
    const float scale = (net==0) ? 0.0625f : 1.0f;
    unsigned short* outp = (net==0 ? qo : ko);
    #pragma unroll
    for (int z = 0; z < 2; z++){
      bfrag pk[2];
      #pragma unroll
      for (int j = 0; j < 16; j++)
        pk[j>>3][j&7] = f2bf((acc[j][z] + bias[j]) * scale);
      size_t dst = ((size_t)(b*T) + t0 + z)*E + e_base;
      *(bfrag*)&outp[dst]     = pk[0];
      *(bfrag*)&outp[dst + 8] = pk[1];
    }
  } else {
    unsigned short* tile = vt + (((size_t)(b*64) + (t0>>5))*256)*32 + (t0 & 31);
    #pragma unroll
    for (int j = 0; j < 16; j++){
      uint32_t pk = (uint32_t)(unsigned short)f2bf(acc[j][0] + bias[j])
                  | ((uint32_t)(unsigned short)f2bf(acc[j][1] + bias[j]) << 16);
      *(uint32_t*)&tile[(size_t)(e_base + j)*32] = pk;
    }
  }
}

// flash attention: r3 structure verbatim (measured 104.6us) with ONE change:
// V staged from V^T tiles via contiguous b128 loads + b128 LDS writes (no gather).
// BQ=128 (8 waves), BK=32, split-K=4. grid = B*16*4 = 512 x 512 thr.
// mfma_f32_16x16x32_bf16: A[m=l16][k=quad*8+j], B[k=quad*8+j][n=l16], D[row=quad*4+reg][col=l16].
__global__ __launch_bounds__(512, 4) void k_attn(
    const unsigned short* __restrict__ qbuf, const unsigned short* __restrict__ kbuf,
    const unsigned short* __restrict__ vt,
    unsigned short* __restrict__ PO_hi, unsigned short* __restrict__ PO_lo,
    float* __restrict__ MLm, float* __restrict__ MLl){
  __shared__ __align__(16) short Ks[32*264];    // K tile, key-major, e fast
  __shared__ __align__(16) short Vs[256*40];    // V^T tile, e-major, key fast
  __shared__ __align__(16) short Ps[8*16*40];   // per-wave P tile

  const int sk   = blockIdx.x & 3;
  const int qt   = (blockIdx.x >> 2) & 15;
  const int b    = blockIdx.x >> 6;
  const int tid  = threadIdx.x;
  const int wave = tid >> 6;
  const int lane = tid & 63;
  const int quad = lane >> 4;
  const int l16  = lane & 15;
  const int qrow_base = qt*128 + wave*16;

  bfrag a_q[8];
  {
    const unsigned short* qrow = qbuf + ((size_t)(b*T) + qrow_base + l16)*E + quad*8;
    #pragma unroll
    for (int kt = 0; kt < 8; kt++)
      a_q[kt] = *(const bfrag*)&qrow[kt*32];
  }

  f32x4 acc_o[16];
  #pragma unroll
  for (int nt = 0; nt < 16; nt++){ f32x4 z = {0.f,0.f,0.f,0.f}; acc_o[nt] = z; }
  float m_run[4] = {-1e30f,-1e30f,-1e30f,-1e30f};
  float l_run[4] = {0.f,0.f,0.f,0.f};

  const int jk = tid >> 3;           // K staging row (K-threads, tid<256)
  const int ec = (tid & 7) * 32;
  const int c0 = tid, c1 = tid + 512;  // V staging chunks (8 shorts each)

  for (int kbk = sk*16; kbk < sk*16 + 16; kbk++){
    const int j0 = kbk*32;
    if (tid < 256){
      const unsigned short* krow = kbuf + ((size_t)(b*T) + j0 + jk)*E + ec;
      #pragma unroll
      for (int u = 0; u < 4; u++)
        *(bfrag*)&Ks[jk*264 + ec + u*8] = *(const bfrag*)&krow[u*8];
    }
    {
      const unsigned short* vtile = vt + (((size_t)(b*64) + kbk)*256)*32;
      *(bfrag*)&Vs[(c0>>2)*40 + (c0&3)*8] = *(const bfrag*)&vtile[c0*8];
      *(bfrag*)&Vs[(c1>>2)*40 + (c1&3)*8] = *(const bfrag*)&vtile[c1*8];
    }
    __syncthreads();

    // S = Q K^T
    f32x4 s0a = {0,0,0,0}, s0b = {0,0,0,0}, s1a = {0,0,0,0}, s1b = {0,0,0,0};
    #pragma unroll
    for (int kt = 0; kt < 8; kt += 2){
      bfrag k0a = *(const bfrag*)&Ks[(l16     )*264 + kt*32 + quad*8];
      bfrag k1a = *(const bfrag*)&Ks[(16 + l16)*264 + kt*32 + quad*8];
      bfrag k0b = *(const bfrag*)&Ks[(l16     )*264 + (kt+1)*32 + quad*8];
      bfrag k1b = *(const bfrag*)&Ks[(16 + l16)*264 + (kt+1)*32 + quad*8];
      s0a = __builtin_amdgcn_mfma_f32_16x16x32_bf16(a_q[kt],   k0a, s0a, 0, 0, 0);
      s1a = __builtin_amdgcn_mfma_f32_16x16x32_bf16(a_q[kt],   k1a, s1a, 0, 0, 0);
      s0b = __builtin_amdgcn_mfma_f32_16x16x32_bf16(a_q[kt+1], k0b, s0b, 0, 0, 0);
      s1b = __builtin_amdgcn_mfma_f32_16x16x32_bf16(a_q[kt+1], k1b, s1b, 0, 0, 0);
    }
    f32x4 sac0 = s0a + s0b, sac1 = s1a + s1b;

    // online softmax (rows = quad*4+rr, cols = l16 / 16+l16)
    float mloc[4], lloc[4], p0[4], p1[4], alpha[4];
    #pragma unroll
    for (int rr = 0; rr < 4; rr++) mloc[rr] = fmaxf(sac0[rr], sac1[rr]);
    #pragma unroll
    for (int off = 1; off < 16; off <<= 1)
      #pragma unroll
      for (int rr = 0; rr < 4; rr++) mloc[rr] = fmaxf(mloc[rr], __shfl_xor(mloc[rr], off));
    #pragma unroll
    for (int rr = 0; rr < 4; rr++){
      float mn = fmaxf(m_run[rr], mloc[rr]);
      alpha[rr] = __expf(m_run[rr] - mn);
      p0[rr] = __expf(sac0[rr] - mn);
      p1[rr] = __expf(sac1[rr] - mn);
      lloc[rr] = p0[rr] + p1[rr];
      m_run[rr] = mn;
    }
    #pragma unroll
    for (int off = 1; off < 16; off <<= 1)
      #pragma unroll
      for (int rr = 0; rr < 4; rr++) lloc[rr] += __shfl_xor(lloc[rr], off);
    #pragma unroll
    for (int rr = 0; rr < 4; rr++) l_run[rr] = l_run[rr]*alpha[rr] + lloc[rr];
    // P -> per-wave LDS (same wave writes & reads; no barrier)
    #pragma unroll
    for (int rr = 0; rr < 4; rr++){
      Ps[(wave*16 + quad*4+rr)*40 + l16]      = f2bf(p0[rr]);
      Ps[(wave*16 + quad*4+rr)*40 + 16 + l16] = f2bf(p1[rr]);
    }
    #pragma unroll
    for (int nt = 0; nt < 16; nt++)
      #pragma unroll
      for (int rr = 0; rr < 4; rr++) acc_o[nt][rr] *= alpha[rr];

    // O += P V
    bfrag pa = *(const bfrag*)&Ps[(wave*16 + l16)*40 + quad*8];
    #pragma unroll
    for (int nt = 0; nt < 16; nt++){
      bfrag vf = *(const bfrag*)&Vs[(nt*16 + l16)*40 + quad*8];
      acc_o[nt] = __builtin_amdgcn_mfma_f32_16x16x32_bf16(pa, vf, acc_o[nt], 0, 0, 0);
    }
    __syncthreads();
  }

  // epilogue: store normalized partial O (bf16) + m,l
  unsigned short* PO = (sk < 3) ? (PO_hi + (size_t)sk*((size_t)B*T*E)) : PO_lo;
  #pragma unroll
  for (int rr = 0; rr < 4; rr++){
    float inv_l = 1.f / l_run[rr];
    const int row = qrow_base + quad*4 + rr;
    const size_t off = ((size_t)(b*T) + row)*E;
    #pragma unroll
    for (int nt = 0; nt < 16; nt++)
      PO[off + nt*16 + l16] = (unsigned short)f2bf(acc_o[nt][rr] * inv_l);
    if (l16 == 0){
      const size_t rm = ((size_t)(sk*B + b))*T + row;
      MLm[rm] = m_run[rr];
      MLl[rm] = l_run[rr];
    }
  }
}

// combine 4 splits + out-projection + RevIN denorm. grid = 512 x 256. [r3-proven]
__global__ __launch_bounds__(256) void k_comb(
    const unsigned short* __restrict__ PO_hi, const unsigned short* __restrict__ PO_lo,
    const float* __restrict__ MLm, const float* __restrict__ MLl,
    const float* __restrict__ out_w, const float* __restrict__ out_b,
    const float* __restrict__ revin_w, const float* __restrict__ revin_b,
    const float* __restrict__ meanp, const float* __restrict__ stdp,
    float* __restrict__ out){
  __shared__ float wsh[3*E];
  for (int i = threadIdx.x; i < 3*E; i += 256) wsh[i] = out_w[i];
  __syncthreads();
  const int b  = blockIdx.x >> 6;
  const int rt = blockIdx.x & 63;
  const int row = rt*32 + (threadIdx.x >> 3);
  const int c8 = threadIdx.x & 7;
  const int e0 = c8*32;
  float ms[4], ls[4], wn[4];
  #pragma unroll
  for (int s2 = 0; s2 < 4; s2++){
    const size_t rm = ((size_t)(s2*B + b))*T + row;
    ms[s2] = MLm[rm]; ls[s2] = MLl[rm];
  }
  float mx = fmaxf(fmaxf(ms[0], ms[1]), fmaxf(ms[2], ms[3]));
  float wsum = 0.f;
  #pragma unroll
  for (int s2 = 0; s2 < 4; s2++){ wn[s2] = __expf(ms[s2]-mx)*ls[s2]; wsum += wn[s2]; }
  float inv = 1.f/wsum;
  #pragma unroll
  for (int s2 = 0; s2 < 4; s2++) wn[s2] *= inv;
  const unsigned short* ps[4];
  #pragma unroll
  for (int s2 = 0; s2 < 4; s2++){
    const unsigned short* base = (s2 < 3) ? (PO_hi + (size_t)s2*((size_t)B*T*E)) : PO_lo;
    ps[s2] = base + ((size_t)(b*T) + row)*E + e0;
  }
  float pr[3] = {0.f, 0.f, 0.f};
  #pragma unroll
  for (int u = 0; u < 4; u++){
    float v[8] = {0,0,0,0,0,0,0,0};
    #pragma unroll
    for (int s2 = 0; s2 < 4; s2++){
      bfrag a = *(const bfrag*)&ps[s2][u*8];
      #pragma unroll
      for (int z = 0; z < 8; z++) v[z] += wn[s2]*bf2f((unsigned short)a[z]);
    }
    #pragma unroll
    for (int z = 0; z < 8; z++){
      int e = e0 + u*8 + z;
      pr[0] += v[z]*wsh[e];
      pr[1] += v[z]*wsh[E + e];
      pr[2] += v[z]*wsh[2*E + e];
    }
  }
  #pragma unroll
  for (int c = 0; c < 3; c++){
    pr[c] += __shfl_xor(pr[c], 1);
    pr[c] += __shfl_xor(pr[c], 2);
    pr[c] += __shfl_xor(pr[c], 4);
  }
  if (c8 == 0){
    #pragma unroll
    for (int c = 0; c < 3; c++){
      float val = pr[c] + out_b[c];
      val = (val - revin_b[c]) / revin_w[c];
      val = val * stdp[b*C + c] + meanp[b*C + c];
      out[((size_t)(b*T) + row)*C + c] = val;
    }
  }
}

} // namespace

extern "C" void kernel_launch(void* const* d_in, const int* in_sizes, int n_in,
                              void* d_out, int out_size, void* d_ws, size_t ws_size,
                              hipStream_t stream){
  const float* query_in = (const float*)d_in[0];
  const float* key_in   = (const float*)d_in[1];
  const float* q_w_in   = (const float*)d_in[2];
  const float* q_b_in   = (const float*)d_in[3];
  const float* q_w_mid  = (const float*)d_in[4];
  const float* q_b_mid  = (const float*)d_in[5];
  const float* q_w_out  = (const float*)d_in[6];
  const float* q_b_out  = (const float*)d_in[7];
  const float* k_w_in   = (const float*)d_in[8];
  const float* k_b_in   = (const float*)d_in[9];
  const float* k_w_mid  = (const float*)d_in[10];
  const float* k_b_mid  = (const float*)d_in[11];
  const float* k_w_out  = (const float*)d_in[12];
  const float* k_b_out  = (const float*)d_in[13];
  const float* v_w_in   = (const float*)d_in[14];
  const float* v_b_in   = (const float*)d_in[15];
  const float* v_w_mid  = (const float*)d_in[16];
  const float* v_b_mid  = (const float*)d_in[17];
  const float* v_w_out  = (const float*)d_in[18];
  const float* v_b_out  = (const float*)d_in[19];
  const float* out_w    = (const float*)d_in[20];
  const float* out_b    = (const float*)d_in[21];
  const float* revin_w  = (const float*)d_in[22];
  const float* revin_b  = (const float*)d_in[23];
  float* ws  = (float*)d_ws;
  float* out = (float*)d_out;

  unsigned short* qb = (unsigned short*)(ws + O_Q);
  unsigned short* kb = (unsigned short*)(ws + O_K);
  unsigned short* vt = (unsigned short*)(ws + O_V);
  unsigned short* PO_hi = (unsigned short*)(ws + O_PO_HI);
  unsigned short* PO_lo = (unsigned short*)(ws + O_PO_LO);
  float* wp_out = ws + O_WP + WP_MID;
  float* MLm = ws + O_MLM;
  float* MLl = ws + O_MLL;

  hipLaunchKernelGGL(k_front, dim3(1020), dim3(256), 0, stream,
                     query_in, key_in, revin_w, revin_b,
                     q_w_mid, k_w_mid, v_w_mid, q_w_out, k_w_out, v_w_out, ws);
  hipLaunchKernelGGL(k_conv_in, dim3(3*B*BN), dim3(256), 0, stream,
                     ws+O_QN, ws+O_KN, q_w_in, q_b_in, k_w_in, k_b_in, v_w_in, v_b_in, ws+O_HA);
  float* ha = ws + O_HA;
  float* hb = ws + O_HB;
  hipLaunchKernelGGL(k_conv_mid<2>,  dim3(384), dim3(256), 0, stream, ha, hb,
                     q_w_mid, k_w_mid, v_w_mid, q_b_mid, k_b_mid, v_b_mid, 0);
  hipLaunchKernelGGL(k_conv_mid<4>,  dim3(384), dim3(256), 0, stream, hb, ha,
                     q_w_mid, k_w_mid, v_w_mid, q_b_mid, k_b_mid, v_b_mid, 1);
  hipLaunchKernelGGL(k_conv_mid<8>,  dim3(384), dim3(256), 0, stream, ha, hb,
                     q_w_mid, k_w_mid, v_w_mid, q_b_mid, k_b_mid, v_b_mid, 2);
  hipLaunchKernelGGL(k_conv_mid<16>, dim3(384), dim3(256), 0, stream, hb, ha,
                     q_w_mid, k_w_mid, v_w_mid, q_b_mid, k_b_mid, v_b_mid, 3);
  hipLaunchKernelGGL(k_conv_mid<32>, dim3(384), dim3(256), 0, stream, ha, hb,
                     q_w_mid, k_w_mid, v_w_mid, q_b_mid, k_b_mid, v_b_mid, 4);
  hipLaunchKernelGGL(k_conv_out, dim3(1536), dim3(256), 0, stream,
                     hb, wp_out, q_b_out, k_b_out, v_b_out, qb, kb, vt);
  hipLaunchKernelGGL(k_attn, dim3(B*16*4), dim3(512), 0, stream, qb, kb, vt, PO_hi, PO_lo, MLm, MLl);
  hipLaunchKernelGGL(k_comb, dim3(B*T/32), dim3(256), 0, stream,
                     PO_hi, PO_lo, MLm, MLl, out_w, out_b, revin_w, revin_b, ws+O_MEAN, ws+O_STD, out);
}